// Round 11
// baseline (458.580 us; speedup 1.0000x reference)
//
#include <hip/hip_runtime.h>
#include <hip/hip_bf16.h>

// Problem constants
#define NB 4
#define NN 256
#define ND 256
#define NL 128
#define NK 256
static constexpr float GAMMA_C = 1e-4f;
static constexpr float ETA_C = 1.0f;

typedef unsigned int u32;
typedef __attribute__((ext_vector_type(8))) short bf16x8;
typedef __attribute__((ext_vector_type(4))) float f32x4;

__device__ __forceinline__ u32 rne1(float x) {            // f32 -> bf16 bits (RNE)
    u32 a = __float_as_uint(x);
    return (a + 0x7FFFu + ((a >> 16) & 1u)) >> 16;
}
__device__ __forceinline__ float bf2f(u32 v) { return __uint_as_float(v << 16); }
// packed f32x2 -> bf16x2 (RNE) -- compiler emits v_cvt_pk_bf16_f32
__device__ __forceinline__ u32 pk2(float lo, float hi) {
    union { __hip_bfloat162 h; u32 u; } cv;
    cv.h = __float22bfloat162_rn(make_float2(lo, hi));
    return cv.u;
}

struct GJob {
    const float* A; const float* W; const float* bias; const float* addm;
    float* C; float* CT; int Kd; int Nc; int relu;
};

// ---------------------------------------------------------------------------
// Generic small GEMM: C[M,Nc] = act(A[M,K] @ W[K,Nc] + bias + addm).
// If CT != nullptr, also writes transposed copy CT[(row>>8)*Nc+col][row&255].
// ---------------------------------------------------------------------------
__device__ __forceinline__ void gemm64_body(
    const float* __restrict__ A, const float* __restrict__ W,
    const float* __restrict__ bias, const float* __restrict__ addm,
    float* __restrict__ C, float* __restrict__ CT, int Kd, int Nc, int relu_act)
{
    __shared__ __align__(16) float As[16][68];
    __shared__ __align__(16) float Ws[16][64];
    int t = threadIdx.x;
    int r0 = blockIdx.x * 64, c0 = blockIdx.y * 64;
    int ty = t >> 4, tx = t & 15;
    float acc[4][4] = {};
    for (int kc = 0; kc < Kd; kc += 16) {
        __syncthreads();
        #pragma unroll
        for (int q = 0; q < 4; ++q) {
            int f = q * 256 + t;
            int row = f >> 4, kk = f & 15;
            As[kk][row] = A[(r0 + row) * Kd + kc + kk];
        }
        #pragma unroll
        for (int q = 0; q < 4; ++q) {
            int f = q * 256 + t;
            int kk = f >> 6, col = f & 63;
            Ws[kk][col] = W[(kc + kk) * Nc + c0 + col];
        }
        __syncthreads();
        #pragma unroll
        for (int kk = 0; kk < 16; ++kk) {
            float4 av = *(const float4*)&As[kk][ty * 4];
            float4 bv = *(const float4*)&Ws[kk][tx * 4];
            float a[4] = {av.x, av.y, av.z, av.w};
            float b[4] = {bv.x, bv.y, bv.z, bv.w};
            #pragma unroll
            for (int i = 0; i < 4; ++i)
                #pragma unroll
                for (int j = 0; j < 4; ++j)
                    acc[i][j] += a[i] * b[j];
        }
    }
    #pragma unroll
    for (int i = 0; i < 4; ++i) {
        int row = r0 + ty * 4 + i;
        #pragma unroll
        for (int j = 0; j < 4; ++j) {
            int col = c0 + tx * 4 + j;
            float v = acc[i][j];
            if (bias) v += bias[col];
            if (addm) v += addm[(row & 255) * Nc + col];
            if (relu_act) v = fmaxf(v, 0.f);
            C[row * Nc + col] = v;
            if (CT) CT[((row >> 8) * Nc + col) * 256 + (row & 255)] = v;
        }
    }
}

__global__ __launch_bounds__(256) void gemm64(
    const float* __restrict__ A, const float* __restrict__ W,
    const float* __restrict__ bias, const float* __restrict__ addm,
    float* __restrict__ C, int M, int Kd, int Nc, int relu_act)
{
    gemm64_body(A, W, bias, addm, C, nullptr, Kd, Nc, relu_act);
}

// Fused multi-GEMM: blockIdx.z selects the job
__global__ __launch_bounds__(256) void gemm64_multi(GJob j0, GJob j1, GJob j2)
{
    GJob jb = (blockIdx.z == 0) ? j0 : (blockIdx.z == 1) ? j1 : j2;
    if ((int)blockIdx.y * 64 >= jb.Nc) return;     // uniform per block
    gemm64_body(jb.A, jb.W, jb.bias, jb.addm, jb.C, jb.CT, jb.Kd, jb.Nc, jb.relu);
}

// ---------------------------------------------------------------------------
// Graph learning: per (b,i) row -> soft_adj, adj2, loss partials.
// xhatT[b][d][j] gives coalesced lane-j reads in the d-loop.
// ---------------------------------------------------------------------------
__global__ __launch_bounds__(256) void soft_adj_kernel(
    const float* __restrict__ xhat, const float* __restrict__ xhatT,
    const float* __restrict__ adj,
    const int* __restrict__ box_num, const float* __restrict__ learn_w,
    float* __restrict__ soft_out, float* __restrict__ adj2,
    float* __restrict__ rowP1, float* __restrict__ rowP2)
{
    __shared__ __align__(16) float xs[NL];
    __shared__ __align__(16) float lw[NL];
    __shared__ float red[256];
    int bi = blockIdx.x;            // b*256 + i
    int b = bi >> 8, i = bi & 255;
    int j = threadIdx.x;
    if (j < NL) { xs[j] = xhat[bi * NL + j]; lw[j] = learn_w[j]; }
    __syncthreads();
    float sumw = 0.f;
    for (int d = 0; d < NL; ++d) sumw += lw[d];
    float s1 = 0.f, s2 = 0.f;
    const float* xT = &xhatT[(size_t)b * NL * 256];
    #pragma unroll 8
    for (int d = 0; d < NL; ++d) {
        float xjv = xT[d * 256 + j];          // coalesced across lanes
        float diff = xs[d] - xjv;
        s1 += fabsf(diff) * lw[d];
        s2 += diff * diff;
    }
    int bn = box_num[b];
    float maskv = (i < bn && j < bn) ? 0.f : -1.f;
    float out = s1 + maskv * sumw;
    out = (out >= 0.f) ? out : 0.01f * out;     // leaky_relu slope 0.01
    float pn = sqrtf(s2 + 1e-12f);
    red[j] = out; __syncthreads();
    for (int s = 128; s > 0; s >>= 1) { if (j < s) red[j] = fmaxf(red[j], red[j + s]); __syncthreads(); }
    float m = red[0]; __syncthreads();
    float aij = adj[bi * 256 + j];
    float e = expf(out - m) * aij;
    red[j] = e; __syncthreads();
    for (int s = 128; s > 0; s >>= 1) { if (j < s) red[j] += red[j + s]; __syncthreads(); }
    float S = red[0]; __syncthreads();
    float soft = e / S + 1e-10f;
    soft_out[bi * 256 + j] = soft;
    adj2[bi * 256 + j] = aij * soft;
    float p1 = expf(soft + ETA_C * pn);
    float p2 = soft * soft;
    red[j] = p1; __syncthreads();
    for (int s = 128; s > 0; s >>= 1) { if (j < s) red[j] += red[j + s]; __syncthreads(); }
    if (j == 0) rowP1[bi] = red[0];
    __syncthreads();
    red[j] = p2; __syncthreads();
    for (int s = 128; s > 0; s >>= 1) { if (j < s) red[j] += red[j + s]; __syncthreads(); }
    if (j == 0) rowP2[bi] = red[0];
}

__global__ __launch_bounds__(256) void gl_loss_kernel(
    const float* __restrict__ rowP1, const float* __restrict__ rowP2,
    const int* __restrict__ box_num, float* __restrict__ out)
{
    __shared__ float r1[256], r2[256];
    int b = blockIdx.x, t = threadIdx.x;
    r1[t] = rowP1[b * 256 + t];
    r2[t] = rowP2[b * 256 + t];
    __syncthreads();
    for (int s = 128; s > 0; s >>= 1) { if (t < s) { r1[t] += r1[t + s]; r2[t] += r2[t + s]; } __syncthreads(); }
    if (t == 0) {
        float bn = (float)box_num[b];
        out[b] = r1[0] / (bn * bn) + GAMMA_C * sqrtf(r2[0]);
    }
}

// ---------------------------------------------------------------------------
// W prep: split w_alpha0 (256x256, k-major) into hi/lo bf16, packed u32 pairs:
//   wTp[hl][c(8)][kgl(4)][n(256)][q(4)], u32 q packs k = c*32+kgl*8+2q, +1
// ---------------------------------------------------------------------------
__global__ __launch_bounds__(256) void wprep(
    const float* __restrict__ w_alpha0, u32* __restrict__ wTp)
{
    int c = blockIdx.x >> 2, kgl = blockIdx.x & 3;
    int n = threadIdx.x;
    #pragma unroll
    for (int q = 0; q < 4; ++q) {
        int k = c * 32 + kgl * 8 + 2 * q;
        float w0 = w_alpha0[k * 256 + n];
        float w1 = w_alpha0[(k + 1) * 256 + n];
        u32 h0 = rne1(w0), h1 = rne1(w1);
        float l0 = w0 - bf2f(h0), l1 = w1 - bf2f(h1);
        wTp[(((0 * 8 + c) * 4 + kgl) * 256 + n) * 4 + q] = h0 | (h1 << 16);
        wTp[(((1 * 8 + c) * 4 + kgl) * 256 + n) * 4 + q] = rne1(l0) | (rne1(l1) << 16);
    }
}

// ---------------------------------------------------------------------------
// Pass 1 (MFMA): per (b, 8i, 8j) tile. H0 on-the-fly -> bf16 in LDS (double-
// buffered, ONE barrier/chunk: writes go to hsA[db^1] while reads of hsA[db]
// are drained by each wave's lgkmcnt(0) at its next barrier arrival —
// race-free). B direct from global wTp (L2). xi/xj prefetched a chunk ahead.
// LDS 33KB + launch_bounds(256,4) -> target 4 blocks/CU (16 waves).
// ---------------------------------------------------------------------------
__global__ __launch_bounds__(256, 4) void pass1M(
    const float* __restrict__ rel, const float* __restrict__ Wat,
    const float* __restrict__ b_alpha, const float* __restrict__ xi0,
    const float* __restrict__ xj0b, const float* __restrict__ adj2,
    const u32* __restrict__ wTp,
    u32* __restrict__ alpha1, float* __restrict__ ahpart)
{
    __shared__ __align__(16) float watb_s[256][8];   // 8KB {Wat[0..5][k], b_alpha[k], 0}
    __shared__ __align__(16) u32 hsA[2][4][64][4];   // 8KB dbuf [db][kgl][m][q]
    __shared__ __align__(16) float st[16][260];      // 16.6KB epilogue staging

    int t = threadIdx.x;
    int jt = blockIdx.x, it = blockIdx.y, b = blockIdx.z;
    int i0 = it * 8, j0 = jt * 8;
    int m = t & 63, wv = t >> 6;       // lane == m; wave id wv
    int ii = m >> 3, jj = m & 7;
    int l4 = m >> 4, l16 = m & 15;

    // block-start staging
    #pragma unroll
    for (int q = 0; q < 8; ++q)
        watb_s[t][q] = (q < 6) ? Wat[q * 256 + t] : (q == 6 ? b_alpha[t] : 0.f);
    float relv2[6];
    #pragma unroll
    for (int c = 0; c < 6; ++c)
        relv2[c] = rel[((b * 256 + i0 + ii) * 256 + j0 + jj) * 6 + c];
    float adjv = adj2[(b * 256 + i0 + ii) * 256 + j0 + jj];
    float* ahbase = &ahpart[(((jt * 4 + b) * 32 + it) * 8 + ii) * 256];
    const float* xirow = &xi0[(b * 256 + i0 + ii) * 256];
    const float* xjrow = &xj0b[(b * 256 + j0 + jj) * 256];

    f32x4 acc[4][4];
    #pragma unroll
    for (int a = 0; a < 4; ++a)
        #pragma unroll
        for (int c = 0; c < 4; ++c)
            acc[a][c] = (f32x4){0.f, 0.f, 0.f, 0.f};

    // prologue prefetch: chunk 0's xi/xj slices
    float4 pxi0 = *(const float4*)&xirow[wv * 8];
    float4 pxi1 = *(const float4*)&xirow[wv * 8 + 4];
    float4 pxj0 = *(const float4*)&xjrow[wv * 8];
    float4 pxj1 = *(const float4*)&xjrow[wv * 8 + 4];

    __syncthreads();   // watb_s ready

    for (int c = 0; c < 8; ++c) {
        int db = c & 1;
        int kb = c * 32 + wv * 8;
        float xiarr[8], xjarr[8];
        xiarr[0]=pxi0.x; xiarr[1]=pxi0.y; xiarr[2]=pxi0.z; xiarr[3]=pxi0.w;
        xiarr[4]=pxi1.x; xiarr[5]=pxi1.y; xiarr[6]=pxi1.z; xiarr[7]=pxi1.w;
        xjarr[0]=pxj0.x; xjarr[1]=pxj0.y; xjarr[2]=pxj0.z; xjarr[3]=pxj0.w;
        xjarr[4]=pxj1.x; xjarr[5]=pxj1.y; xjarr[6]=pxj1.z; xjarr[7]=pxj1.w;
        if (c < 7) {   // prefetch next chunk (latency hides under this chunk)
            int kn = kb + 32;
            pxi0 = *(const float4*)&xirow[kn];
            pxi1 = *(const float4*)&xirow[kn + 4];
            pxj0 = *(const float4*)&xjrow[kn];
            pxj1 = *(const float4*)&xjrow[kn + 4];
        }
        float h[8];
        #pragma unroll
        for (int i = 0; i < 8; ++i) {
            int k = kb + i;
            float4 wa = *(const float4*)&watb_s[k][0];   // uniform-address broadcast
            float4 wc = *(const float4*)&watb_s[k][4];
            float a = relv2[0]*wa.x + relv2[1]*wa.y + relv2[2]*wa.z + relv2[3]*wa.w
                    + relv2[4]*wc.x + relv2[5]*wc.y + wc.z;   // wc.z = b_alpha[k]
            h[i] = fmaxf(xiarr[i] + xjarr[i] + a, 0.f);
        }
        // ---- AH0 partial: butterfly over jj, lane jj keeps element jj ----
        {
            float ahv = 0.f;
            #pragma unroll
            for (int i = 0; i < 8; ++i) {
                float v = adjv * h[i];
                v += __shfl_xor(v, 1);
                v += __shfl_xor(v, 2);
                v += __shfl_xor(v, 4);
                ahv = (jj == i) ? v : ahv;
            }
            ahbase[kb + jj] = ahv;
        }
        // ---- bf16 pack (hi only), write to hsA[db] ----
        {
            u32 hi[4];
            #pragma unroll
            for (int p = 0; p < 4; ++p)
                hi[p] = pk2(h[2*p], h[2*p+1]);
            *(uint4*)&hsA[db][wv][m][0] = make_uint4(hi[0], hi[1], hi[2], hi[3]);
        }
        __syncthreads();   // hsA[db] ready — single barrier per chunk (dbuf)

        // ---- fragments + MFMA: A from LDS, B straight from global (L1/L2) ----
        bf16x8 aH[4];
        #pragma unroll
        for (int mt = 0; mt < 4; ++mt)
            aH[mt] = *(const bf16x8*)&hsA[db][l4][mt * 16 + l16][0];
        const u32* wc0 = &wTp[(c * 4 + l4) * 1024];          // hl=0 chunk base
        const u32* wc1 = &wTp[((8 + c) * 4 + l4) * 1024];    // hl=1 chunk base
        #pragma unroll
        for (int ntl = 0; ntl < 4; ++ntl) {
            int n = (wv * 4 + ntl) * 16 + l16;
            bf16x8 bH = *(const bf16x8*)&wc0[n * 4];
            bf16x8 bL = *(const bf16x8*)&wc1[n * 4];
            #pragma unroll
            for (int mt = 0; mt < 4; ++mt) {
                acc[mt][ntl] = __builtin_amdgcn_mfma_f32_16x16x32_bf16(aH[mt], bH, acc[mt][ntl], 0, 0, 0);
                acc[mt][ntl] = __builtin_amdgcn_mfma_f32_16x16x32_bf16(aH[mt], bL, acc[mt][ntl], 0, 0, 0);
            }
        }
        // no trailing barrier: next chunk writes hsA[db^1]
    }

    // ---- epilogue: relu + bf16-pack alpha1 via LDS staging (st disjoint from
    // hsA; per-thread st writes are disjoint; barrier precedes cross-reads) ----
    #pragma unroll
    for (int mt = 0; mt < 4; ++mt) {
        #pragma unroll
        for (int ntl = 0; ntl < 4; ++ntl) {
            int n = (wv * 4 + ntl) * 16 + l16;
            #pragma unroll
            for (int r = 0; r < 4; ++r)
                st[l4 * 4 + r][n] = acc[mt][ntl][r];
        }
        __syncthreads();
        #pragma unroll
        for (int p = 0; p < 2; ++p) {
            int f = p * 256 + t;                     // 0..511
            int row = f >> 5, u8 = f & 31;           // row 0..15, 8 f32 each
            float4 c0 = *(const float4*)&st[row][u8 * 8];
            float4 c1 = *(const float4*)&st[row][u8 * 8 + 4];
            uint4 pk;
            pk.x = pk2(fmaxf(c0.x, 0.f), fmaxf(c0.y, 0.f));
            pk.y = pk2(fmaxf(c0.z, 0.f), fmaxf(c0.w, 0.f));
            pk.z = pk2(fmaxf(c1.x, 0.f), fmaxf(c1.y, 0.f));
            pk.w = pk2(fmaxf(c1.z, 0.f), fmaxf(c1.w, 0.f));
            int mg = mt * 16 + row;                  // pair row 0..63
            int iw = mg >> 3, jw = mg & 7;
            *(uint4*)&alpha1[((b * 256 + i0 + iw) * 256 + j0 + jw) * 128 + u8 * 4] = pk;
        }
        __syncthreads();
    }
}

// ---------------------------------------------------------------------------
// post0: 4 rows per block (weights read once per 4 rows -> 4x less L2 traffic).
// Fuses: reduce_ah -> x1 = relu(AH0 @ w_node0) -> xi1/xj1b projections.
// Per-row FMA order identical to 1-row version (bit-identical results).
// ---------------------------------------------------------------------------
__global__ __launch_bounds__(256) void post0(
    const float* __restrict__ part, const float* __restrict__ w_node0,
    const float* __restrict__ w_vi1, const float* __restrict__ w_vj1,
    const float* __restrict__ bias_h1,
    float* __restrict__ xi1, float* __restrict__ xj1b)
{
    __shared__ __align__(16) float ah_s[4][256];
    __shared__ __align__(16) float x1_s[4][256];
    int bi0 = blockIdx.x * 4;          // 256 blocks; 4 consecutive rows, same b
    int b = bi0 >> 8;
    int t = threadIdx.x;
    #pragma unroll
    for (int r = 0; r < 4; ++r) {
        int i = (bi0 + r) & 255;
        int it = i >> 3, ii = i & 7;
        float s = 0.f;
        #pragma unroll 4
        for (int jt = 0; jt < 32; ++jt)
            s += part[(((jt * 4 + b) * 32 + it) * 8 + ii) * 256 + t];
        ah_s[r][t] = s;
    }
    __syncthreads();
    float a0[4] = {};
    #pragma unroll 8
    for (int k = 0; k < 256; ++k) {
        float w0 = w_node0[k * 256 + t];
        #pragma unroll
        for (int r = 0; r < 4; ++r) a0[r] += ah_s[r][k] * w0;
    }
    #pragma unroll
    for (int r = 0; r < 4; ++r) x1_s[r][t] = fmaxf(a0[r], 0.f);
    __syncthreads();
    float a1[4] = {}, a2[4] = {};
    #pragma unroll 8
    for (int k = 0; k < 256; ++k) {
        float w1 = w_vi1[k * 256 + t];
        float w2 = w_vj1[k * 256 + t];
        #pragma unroll
        for (int r = 0; r < 4; ++r) {
            float xv = x1_s[r][k];
            a1[r] += xv * w1;
            a2[r] += xv * w2;
        }
    }
    #pragma unroll
    for (int r = 0; r < 4; ++r) {
        int i = (bi0 + r) & 255;
        xi1[(bi0 + r) * 256 + t] = a1[r];
        xj1b[(bi0 + r) * 256 + t] = a2[r] + bias_h1[i * 256 + t];
    }
}

// ---------------------------------------------------------------------------
// pass2x: 2 rows per block (xj1b + w_node1 read once for both rows).
// Stream bf16 alpha1, accumulate AH1, fused final x2 = relu(AH1 @ w_node1).
// ---------------------------------------------------------------------------
__global__ __launch_bounds__(256) void pass2x(
    const u32* __restrict__ alpha1, const float* __restrict__ xi1,
    const float* __restrict__ xj1b, const float* __restrict__ adj2,
    const float* __restrict__ w_node1, float* __restrict__ x2)
{
    __shared__ __align__(16) float partial[4][2][256];
    __shared__ __align__(16) float ah1_s[2][256];
    int bi0 = blockIdx.x * 2;          // 512 blocks; rows bi0, bi0+1 (same b)
    int b = bi0 >> 8;
    int t = threadIdx.x;
    int wv = t >> 6, lane = t & 63;
    int k4 = lane * 4;
    float4 xiA = *(const float4*)&xi1[bi0 * 256 + k4];
    float4 xiB = *(const float4*)&xi1[(bi0 + 1) * 256 + k4];
    float4 accA = {0.f, 0.f, 0.f, 0.f};
    float4 accB = {0.f, 0.f, 0.f, 0.f};
    size_t baseA = (size_t)bi0 * 32768;   // u32 units: 256*128
    size_t baseB = baseA + 32768;
    const float* a2A = &adj2[bi0 * 256];
    const float* a2B = a2A + 256;
    for (int j = wv; j < 256; j += 4) {
        float4 xj = *(const float4*)&xj1b[(b * 256 + j) * 256 + k4];
        float aA = a2A[j], aB = a2B[j];
        uint2 qA = *(const uint2*)&alpha1[baseA + j * 128 + (k4 >> 1)];
        uint2 qB = *(const uint2*)&alpha1[baseB + j * 128 + (k4 >> 1)];
        float4 alA, alB;
        alA.x = bf2f(qA.x & 0xFFFFu); alA.y = bf2f(qA.x >> 16);
        alA.z = bf2f(qA.y & 0xFFFFu); alA.w = bf2f(qA.y >> 16);
        alB.x = bf2f(qB.x & 0xFFFFu); alB.y = bf2f(qB.x >> 16);
        alB.z = bf2f(qB.y & 0xFFFFu); alB.w = bf2f(qB.y >> 16);
        accA.x += aA * fmaxf(xiA.x + xj.x + alA.x, 0.f);
        accA.y += aA * fmaxf(xiA.y + xj.y + alA.y, 0.f);
        accA.z += aA * fmaxf(xiA.z + xj.z + alA.z, 0.f);
        accA.w += aA * fmaxf(xiA.w + xj.w + alA.w, 0.f);
        accB.x += aB * fmaxf(xiB.x + xj.x + alB.x, 0.f);
        accB.y += aB * fmaxf(xiB.y + xj.y + alB.y, 0.f);
        accB.z += aB * fmaxf(xiB.z + xj.z + alB.z, 0.f);
        accB.w += aB * fmaxf(xiB.w + xj.w + alB.w, 0.f);
    }
    *(float4*)&partial[wv][0][k4] = accA;
    *(float4*)&partial[wv][1][k4] = accB;
    __syncthreads();
    ah1_s[0][t] = partial[0][0][t] + partial[1][0][t] + partial[2][0][t] + partial[3][0][t];
    ah1_s[1][t] = partial[0][1][t] + partial[1][1][t] + partial[2][1][t] + partial[3][1][t];
    __syncthreads();
    float o0 = 0.f, o1 = 0.f;
    #pragma unroll 8
    for (int k = 0; k < 256; ++k) {
        float w = w_node1[k * 256 + t];
        o0 += ah1_s[0][k] * w;
        o1 += ah1_s[1][k] * w;
    }
    x2[bi0 * 256 + t] = fmaxf(o0, 0.f);
    x2[(bi0 + 1) * 256 + t] = fmaxf(o1, 0.f);
}

// ---------------------------------------------------------------------------
// Tier C fallback kernels (tiny-ws path)
// ---------------------------------------------------------------------------
__global__ __launch_bounds__(256) void pass1C(
    const float* __restrict__ rel, const float* __restrict__ Wat,
    const float* __restrict__ b_alpha, const float* __restrict__ xi0,
    const float* __restrict__ xj0b, const float* __restrict__ adj2,
    float* __restrict__ AH0)
{
    __shared__ float xj_s[16][257];
    __shared__ float rel_s[16 * 48];
    __shared__ float adj_sC[128];
    int t = threadIdx.x;
    int it = blockIdx.x, b = blockIdx.y;
    int i0 = it * 8;
    float xiv[8], watv[6];
    #pragma unroll
    for (int ii = 0; ii < 8; ++ii) xiv[ii] = xi0[(b * 256 + i0 + ii) * 256 + t];
    #pragma unroll
    for (int c = 0; c < 6; ++c) watv[c] = Wat[c * 256 + t];
    float bav = b_alpha[t];
    float ah[8] = {};
    for (int jc = 0; jc < 256; jc += 16) {
        __syncthreads();
        #pragma unroll
        for (int q = 0; q < 16; ++q) xj_s[q][t] = xj0b[(b * 256 + jc + q) * 256 + t];
        for (int e = t; e < 768; e += 256) {
            int jjp = e / 48, r = e % 48;
            rel_s[e] = rel[((b * 256 + i0 + r / 6) * 256 + jc + jjp) * 6 + (r % 6)];
        }
        if (t < 128) adj_sC[t] = adj2[(b * 256 + i0 + (t & 7)) * 256 + jc + (t >> 3)];
        __syncthreads();
        for (int jjp = 0; jjp < 16; ++jjp) {
            float xjv = xj_s[jjp][t];
            #pragma unroll
            for (int ii = 0; ii < 8; ++ii) {
                float a = bav;
                #pragma unroll
                for (int c = 0; c < 6; ++c) a += rel_s[jjp * 48 + ii * 6 + c] * watv[c];
                float h = fmaxf(xiv[ii] + xjv + a, 0.f);
                ah[ii] += adj_sC[jjp * 8 + ii] * h;
            }
        }
    }
    #pragma unroll
    for (int ii = 0; ii < 8; ++ii)
        AH0[(b * 256 + i0 + ii) * 256 + t] = ah[ii];
}

__global__ __launch_bounds__(256) void pass2C(
    const float* __restrict__ rel, const float* __restrict__ Wat,
    const float* __restrict__ b_alpha, const float* __restrict__ xi0,
    const float* __restrict__ xj0b, const float* __restrict__ w_alpha0,
    const float* __restrict__ xi1, const float* __restrict__ xj1b,
    const float* __restrict__ adj2, float* __restrict__ AH1)
{
    __shared__ float xi_s[8][257];
    __shared__ float xj_s[8][257];
    __shared__ float xj1_s[8][257];
    __shared__ __align__(16) float wat_s[6][256];
    __shared__ __align__(16) float ba_s[256];
    __shared__ __align__(16) float rel_s[6][64];
    __shared__ __align__(16) float adj_s[64];
    __shared__ __align__(16) float hs[16][64];
    __shared__ __align__(16) float ws_s[16][256];

    int t = threadIdx.x;
    int it = blockIdx.x, b = blockIdx.y;
    int i0 = it * 8;
    int rg = t >> 5, cg = t & 31;
    int lane = t & 63, wv = t >> 6;
    int ii_l = lane >> 3, jj_l = lane & 7;

    #pragma unroll
    for (int q = 0; q < 8; ++q) xi_s[q][t] = xi0[(b * 256 + i0 + q) * 256 + t];
    #pragma unroll
    for (int q = 0; q < 6; ++q) wat_s[q][t] = Wat[q * 256 + t];
    ba_s[t] = b_alpha[t];
    float xi1v[8];
    #pragma unroll
    for (int y = 0; y < 8; ++y) xi1v[y] = xi1[(b * 256 + i0 + rg) * 256 + cg * 8 + y];
    float ah1[8] = {};

    for (int jt = 0; jt < 32; ++jt) {
        int j0 = jt * 8;
        __syncthreads();
        #pragma unroll
        for (int q = 0; q < 8; ++q) {
            xj_s[q][t]  = xj0b[(b * 256 + j0 + q) * 256 + t];
            xj1_s[q][t] = xj1b[(b * 256 + j0 + q) * 256 + t];
        }
        for (int e = t; e < 384; e += 256) {
            int ii = e / 48, rem = e % 48;
            int jjp = rem / 6, c = rem % 6;
            rel_s[c][ii * 8 + jjp] = rel[((b * 256 + i0 + ii) * 256 + j0 + jjp) * 6 + c];
        }
        if (t < 64) adj_s[t] = adj2[(b * 256 + i0 + (t >> 3)) * 256 + j0 + (t & 7)];

        float acc[8][8] = {};
        for (int c = 0; c < 16; ++c) {
            __syncthreads();
            #pragma unroll
            for (int p = 0; p < 4; ++p) {
                int klocal = wv + p * 4;
                int kg = c * 16 + klocal;
                float a = ba_s[kg];
                #pragma unroll
                for (int cc = 0; cc < 6; ++cc) a += rel_s[cc][lane] * wat_s[cc][kg];
                float h = xi_s[ii_l][kg] + xj_s[jj_l][kg] + a;
                hs[klocal][lane] = fmaxf(h, 0.f);
            }
            #pragma unroll
            for (int q = 0; q < 4; ++q) {
                int f = q * 256 + t;
                int row = f >> 6, col4 = f & 63;
                *(float4*)&ws_s[row][col4 * 4] =
                    *(const float4*)&w_alpha0[(c * 16 + row) * 256 + col4 * 4];
            }
            __syncthreads();
            #pragma unroll
            for (int kk = 0; kk < 16; ++kk) {
                float4 a0 = *(const float4*)&hs[kk][rg * 8];
                float4 a1 = *(const float4*)&hs[kk][rg * 8 + 4];
                float4 b0 = *(const float4*)&ws_s[kk][cg * 8];
                float4 b1 = *(const float4*)&ws_s[kk][cg * 8 + 4];
                float av[8] = {a0.x, a0.y, a0.z, a0.w, a1.x, a1.y, a1.z, a1.w};
                float bv[8] = {b0.x, b0.y, b0.z, b0.w, b1.x, b1.y, b1.z, b1.w};
                #pragma unroll
                for (int x = 0; x < 8; ++x)
                    #pragma unroll
                    for (int y = 0; y < 8; ++y)
                        acc[x][y] += av[x] * bv[y];
            }
        }
        #pragma unroll
        for (int x = 0; x < 8; ++x) {
            float a2 = adj_s[rg * 8 + x];
            #pragma unroll
            for (int y = 0; y < 8; ++y) {
                float al = fmaxf(acc[x][y], 0.f);
                float h1 = fmaxf(xi1v[y] + xj1_s[x][cg * 8 + y] + al, 0.f);
                ah1[y] += a2 * h1;
            }
        }
    }
    #pragma unroll
    for (int y = 0; y < 8; ++y)
        AH1[(b * 256 + i0 + rg) * 256 + cg * 8 + y] = ah1[y];
}

// ---------------------------------------------------------------------------
extern "C" void kernel_launch(void* const* d_in, const int* in_sizes, int n_in,
                              void* d_out, int out_size, void* d_ws, size_t ws_size,
                              hipStream_t stream)
{
    const float* x        = (const float*)d_in[0];
    const float* rel      = (const float*)d_in[1];
    const float* adj      = (const float*)d_in[2];
    const int*   box_num  = (const int*)d_in[3];
    const float* Wat      = (const float*)d_in[4];
    const float* b_alpha  = (const float*)d_in[5];
    const float* W_proj   = (const float*)d_in[6];
    const float* b_proj   = (const float*)d_in[7];
    const float* learn_w  = (const float*)d_in[8];
    const float* w_alpha0 = (const float*)d_in[9];
    const float* w_vi0    = (const float*)d_in[10];
    const float* w_vj0    = (const float*)d_in[11];
    const float* bias_h0  = (const float*)d_in[12];
    const float* w_node0  = (const float*)d_in[13];
    // d_in[14] = l1_w_alpha (unused: layer-1 new_alpha is discarded)
    const float* w_vi1    = (const float*)d_in[15];
    const float* w_vj1    = (const float*)d_in[16];
    const float* bias_h1  = (const float*)d_in[17];
    const float* w_node1  = (const float*)d_in[18];

    // ---- workspace layout ----
    float* sm    = (float*)d_ws;
    float* adj2  = sm;                 // 262,144
    float* xhat  = adj2  + 262144;     // 131,072
    float* xi0   = xhat  + 131072;     // 262,144
    float* xj0b  = xi0   + 262144;     // 262,144
    float* AH0   = xj0b  + 262144;     // 262,144 (fallback AH0; mfma path uses as xhatT)
    float* x1    = AH0   + 262144;     // 262,144 (fallback path only)
    float* xi1   = x1    + 262144;     // 262,144
    float* xj1b  = xi1   + 262144;     // 262,144
    float* AH1   = xj1b  + 262144;     // 262,144 (fallback path only)
    float* rowP1 = AH1   + 262144;     //   1,024
    float* rowP2 = rowP1 + 1024;       //   1,024
    float* xhatT = AH0;                // alias: consumed before pass1C writes AH0
    const size_t SMALLS_F = 2230272;   // floats
    const size_t WTP_F    = 65536;     // 256 KB packed hi/lo W
    const size_t PART_F   = 8388608;
    u32*   wTp    = (u32*)(sm + SMALLS_F);
    float* part   = sm + SMALLS_F + WTP_F;
    u32*   alpha1 = (u32*)(sm + SMALLS_F + WTP_F + PART_F);   // bf16-packed, 128 MiB

    const size_t needM = (SMALLS_F + WTP_F + PART_F) * 4ULL + 134217728ULL;  // ~169 MB
    int use_mfma = (ws_size >= needM);

    float* out_x2   = (float*)d_out;
    float* out_soft = out_x2 + 262144;
    float* out_gl   = out_soft + 262144;

    // W prep (independent of everything else) first
    if (use_mfma) wprep<<<32, 256, 0, stream>>>(w_alpha0, wTp);

    // Phase A projections, fused: xhat (+xhatT) + xi0 + xj0b
    {
        GJob ja{x, W_proj, b_proj, nullptr, xhat, xhatT, 256, 128, 0};
        GJob jb{x, w_vi0,  nullptr, nullptr, xi0,  nullptr, 256, 256, 0};
        GJob jc{x, w_vj0,  nullptr, bias_h0, xj0b, nullptr, 256, 256, 0};
        gemm64_multi<<<dim3(16, 4, 3), 256, 0, stream>>>(ja, jb, jc);
    }
    soft_adj_kernel<<<1024, 256, 0, stream>>>(xhat, xhatT, adj, box_num, learn_w, out_soft, adj2, rowP1, rowP2);
    gl_loss_kernel<<<4, 256, 0, stream>>>(rowP1, rowP2, box_num, out_gl);

    if (use_mfma) {
        // Layer 0 heavy pass -> alpha1 (bf16) + AH0 partials
        pass1M<<<dim3(32, 32, 4), 256, 0, stream>>>(rel, Wat, b_alpha, xi0, xj0b, adj2, wTp, alpha1, part);
        // Fused: reduce AH0 -> x1 -> xi1/xj1b (4 rows/block)
        post0<<<256, 256, 0, stream>>>(part, w_node0, w_vi1, w_vj1, bias_h1, xi1, xj1b);
        // Layer 1 + fused final node update -> x2 (2 rows/block)
        pass2x<<<512, 256, 0, stream>>>(alpha1, xi1, xj1b, adj2, w_node1, out_x2);
    } else {
        pass1C<<<dim3(32, 4), 256, 0, stream>>>(rel, Wat, b_alpha, xi0, xj0b, adj2, AH0);
        gemm64<<<dim3(16, 4), 256, 0, stream>>>(AH0, w_node0, nullptr, nullptr, x1, 1024, 256, 256, 1);
        {
            GJob j1a{x1, w_vi1, nullptr, nullptr, xi1,  nullptr, 256, 256, 0};
            GJob j1b{x1, w_vj1, nullptr, bias_h1, xj1b, nullptr, 256, 256, 0};
            gemm64_multi<<<dim3(16, 4, 2), 256, 0, stream>>>(j1a, j1b, j1b);
        }
        pass2C<<<dim3(32, 4), 256, 0, stream>>>(rel, Wat, b_alpha, xi0, xj0b, w_alpha0, xi1, xj1b, adj2, AH1);
        gemm64<<<dim3(16, 4), 256, 0, stream>>>(AH1, w_node1, nullptr, nullptr, out_x2, 1024, 256, 256, 1);
    }
}

// Round 12
// 399.858 us; speedup vs baseline: 1.1469x; 1.1469x over previous
//
#include <hip/hip_runtime.h>
#include <hip/hip_bf16.h>

// Problem constants
#define NB 4
#define NN 256
#define ND 256
#define NL 128
#define NK 256
static constexpr float GAMMA_C = 1e-4f;
static constexpr float ETA_C = 1.0f;

typedef unsigned int u32;
typedef __attribute__((ext_vector_type(8))) short bf16x8;
typedef __attribute__((ext_vector_type(4))) float f32x4;

__device__ __forceinline__ u32 rne1(float x) {            // f32 -> bf16 bits (RNE)
    u32 a = __float_as_uint(x);
    return (a + 0x7FFFu + ((a >> 16) & 1u)) >> 16;
}
__device__ __forceinline__ float bf2f(u32 v) { return __uint_as_float(v << 16); }
// packed f32x2 -> bf16x2 (RNE) -- compiler emits v_cvt_pk_bf16_f32
__device__ __forceinline__ u32 pk2(float lo, float hi) {
    union { __hip_bfloat162 h; u32 u; } cv;
    cv.h = __float22bfloat162_rn(make_float2(lo, hi));
    return cv.u;
}

struct GJob {
    const float* A; const float* W; const float* bias; const float* addm;
    float* C; float* CT; int Kd; int Nc; int relu;
};

// ---------------------------------------------------------------------------
// Generic small GEMM: C[M,Nc] = act(A[M,K] @ W[K,Nc] + bias + addm).
// If CT != nullptr, also writes transposed copy CT[(row>>8)*Nc+col][row&255].
// ---------------------------------------------------------------------------
__device__ __forceinline__ void gemm64_body(
    const float* __restrict__ A, const float* __restrict__ W,
    const float* __restrict__ bias, const float* __restrict__ addm,
    float* __restrict__ C, float* __restrict__ CT, int Kd, int Nc, int relu_act)
{
    __shared__ __align__(16) float As[16][68];
    __shared__ __align__(16) float Ws[16][64];
    int t = threadIdx.x;
    int r0 = blockIdx.x * 64, c0 = blockIdx.y * 64;
    int ty = t >> 4, tx = t & 15;
    float acc[4][4] = {};
    for (int kc = 0; kc < Kd; kc += 16) {
        __syncthreads();
        #pragma unroll
        for (int q = 0; q < 4; ++q) {
            int f = q * 256 + t;
            int row = f >> 4, kk = f & 15;
            As[kk][row] = A[(r0 + row) * Kd + kc + kk];
        }
        #pragma unroll
        for (int q = 0; q < 4; ++q) {
            int f = q * 256 + t;
            int kk = f >> 6, col = f & 63;
            Ws[kk][col] = W[(kc + kk) * Nc + c0 + col];
        }
        __syncthreads();
        #pragma unroll
        for (int kk = 0; kk < 16; ++kk) {
            float4 av = *(const float4*)&As[kk][ty * 4];
            float4 bv = *(const float4*)&Ws[kk][tx * 4];
            float a[4] = {av.x, av.y, av.z, av.w};
            float b[4] = {bv.x, bv.y, bv.z, bv.w};
            #pragma unroll
            for (int i = 0; i < 4; ++i)
                #pragma unroll
                for (int j = 0; j < 4; ++j)
                    acc[i][j] += a[i] * b[j];
        }
    }
    #pragma unroll
    for (int i = 0; i < 4; ++i) {
        int row = r0 + ty * 4 + i;
        #pragma unroll
        for (int j = 0; j < 4; ++j) {
            int col = c0 + tx * 4 + j;
            float v = acc[i][j];
            if (bias) v += bias[col];
            if (addm) v += addm[(row & 255) * Nc + col];
            if (relu_act) v = fmaxf(v, 0.f);
            C[row * Nc + col] = v;
            if (CT) CT[((row >> 8) * Nc + col) * 256 + (row & 255)] = v;
        }
    }
}

__global__ __launch_bounds__(256) void gemm64(
    const float* __restrict__ A, const float* __restrict__ W,
    const float* __restrict__ bias, const float* __restrict__ addm,
    float* __restrict__ C, int M, int Kd, int Nc, int relu_act)
{
    gemm64_body(A, W, bias, addm, C, nullptr, Kd, Nc, relu_act);
}

// Fused multi-GEMM: blockIdx.z selects the job
__global__ __launch_bounds__(256) void gemm64_multi(GJob j0, GJob j1, GJob j2)
{
    GJob jb = (blockIdx.z == 0) ? j0 : (blockIdx.z == 1) ? j1 : j2;
    if ((int)blockIdx.y * 64 >= jb.Nc) return;     // uniform per block
    gemm64_body(jb.A, jb.W, jb.bias, jb.addm, jb.C, jb.CT, jb.Kd, jb.Nc, jb.relu);
}

// ---------------------------------------------------------------------------
// Graph learning: per (b,i) row -> soft_adj, adj2, loss partials.
// xhatT[b][d][j] gives coalesced lane-j reads in the d-loop.
// ---------------------------------------------------------------------------
__global__ __launch_bounds__(256) void soft_adj_kernel(
    const float* __restrict__ xhat, const float* __restrict__ xhatT,
    const float* __restrict__ adj,
    const int* __restrict__ box_num, const float* __restrict__ learn_w,
    float* __restrict__ soft_out, float* __restrict__ adj2,
    float* __restrict__ rowP1, float* __restrict__ rowP2)
{
    __shared__ __align__(16) float xs[NL];
    __shared__ __align__(16) float lw[NL];
    __shared__ float red[256];
    int bi = blockIdx.x;            // b*256 + i
    int b = bi >> 8, i = bi & 255;
    int j = threadIdx.x;
    if (j < NL) { xs[j] = xhat[bi * NL + j]; lw[j] = learn_w[j]; }
    __syncthreads();
    float sumw = 0.f;
    for (int d = 0; d < NL; ++d) sumw += lw[d];
    float s1 = 0.f, s2 = 0.f;
    const float* xT = &xhatT[(size_t)b * NL * 256];
    #pragma unroll 8
    for (int d = 0; d < NL; ++d) {
        float xjv = xT[d * 256 + j];          // coalesced across lanes
        float diff = xs[d] - xjv;
        s1 += fabsf(diff) * lw[d];
        s2 += diff * diff;
    }
    int bn = box_num[b];
    float maskv = (i < bn && j < bn) ? 0.f : -1.f;
    float out = s1 + maskv * sumw;
    out = (out >= 0.f) ? out : 0.01f * out;     // leaky_relu slope 0.01
    float pn = sqrtf(s2 + 1e-12f);
    red[j] = out; __syncthreads();
    for (int s = 128; s > 0; s >>= 1) { if (j < s) red[j] = fmaxf(red[j], red[j + s]); __syncthreads(); }
    float m = red[0]; __syncthreads();
    float aij = adj[bi * 256 + j];
    float e = expf(out - m) * aij;
    red[j] = e; __syncthreads();
    for (int s = 128; s > 0; s >>= 1) { if (j < s) red[j] += red[j + s]; __syncthreads(); }
    float S = red[0]; __syncthreads();
    float soft = e / S + 1e-10f;
    soft_out[bi * 256 + j] = soft;
    adj2[bi * 256 + j] = aij * soft;
    float p1 = expf(soft + ETA_C * pn);
    float p2 = soft * soft;
    red[j] = p1; __syncthreads();
    for (int s = 128; s > 0; s >>= 1) { if (j < s) red[j] += red[j + s]; __syncthreads(); }
    if (j == 0) rowP1[bi] = red[0];
    __syncthreads();
    red[j] = p2; __syncthreads();
    for (int s = 128; s > 0; s >>= 1) { if (j < s) red[j] += red[j + s]; __syncthreads(); }
    if (j == 0) rowP2[bi] = red[0];
}

__global__ __launch_bounds__(256) void gl_loss_kernel(
    const float* __restrict__ rowP1, const float* __restrict__ rowP2,
    const int* __restrict__ box_num, float* __restrict__ out)
{
    __shared__ float r1[256], r2[256];
    int b = blockIdx.x, t = threadIdx.x;
    r1[t] = rowP1[b * 256 + t];
    r2[t] = rowP2[b * 256 + t];
    __syncthreads();
    for (int s = 128; s > 0; s >>= 1) { if (t < s) { r1[t] += r1[t + s]; r2[t] += r2[t + s]; } __syncthreads(); }
    if (t == 0) {
        float bn = (float)box_num[b];
        out[b] = r1[0] / (bn * bn) + GAMMA_C * sqrtf(r2[0]);
    }
}

// ---------------------------------------------------------------------------
// W prep: split w_alpha0 (256x256, k-major) into hi/lo bf16, packed u32 pairs:
//   wTp[hl][c(8)][kgl(4)][n(256)][q(4)], u32 q packs k = c*32+kgl*8+2q, +1
// ---------------------------------------------------------------------------
__global__ __launch_bounds__(256) void wprep(
    const float* __restrict__ w_alpha0, u32* __restrict__ wTp)
{
    int c = blockIdx.x >> 2, kgl = blockIdx.x & 3;
    int n = threadIdx.x;
    #pragma unroll
    for (int q = 0; q < 4; ++q) {
        int k = c * 32 + kgl * 8 + 2 * q;
        float w0 = w_alpha0[k * 256 + n];
        float w1 = w_alpha0[(k + 1) * 256 + n];
        u32 h0 = rne1(w0), h1 = rne1(w1);
        float l0 = w0 - bf2f(h0), l1 = w1 - bf2f(h1);
        wTp[(((0 * 8 + c) * 4 + kgl) * 256 + n) * 4 + q] = h0 | (h1 << 16);
        wTp[(((1 * 8 + c) * 4 + kgl) * 256 + n) * 4 + q] = rne1(l0) | (rne1(l1) << 16);
    }
}

// ---------------------------------------------------------------------------
// Pass 1 (MFMA): per (b, 8i, 8j) tile. H0 on-the-fly -> bf16 in LDS (double-
// buffered, ONE barrier/chunk: writes go to hsA[db^1] while reads of hsA[db]
// are drained by each wave's lgkmcnt(0) at its next barrier arrival —
// race-free). B direct from global wTp (L2). xi/xj prefetched a chunk ahead.
// launch_bounds(256,3): round-11 showed (256,4) forces ~30-value spill
// (WRITE_SIZE 164->361MB); acc[4][4]=64 unified regs is incompressible.
// ---------------------------------------------------------------------------
__global__ __launch_bounds__(256, 3) void pass1M(
    const float* __restrict__ rel, const float* __restrict__ Wat,
    const float* __restrict__ b_alpha, const float* __restrict__ xi0,
    const float* __restrict__ xj0b, const float* __restrict__ adj2,
    const u32* __restrict__ wTp,
    u32* __restrict__ alpha1, float* __restrict__ ahpart)
{
    __shared__ __align__(16) float watb_s[256][8];   // 8KB {Wat[0..5][k], b_alpha[k], 0}
    __shared__ __align__(16) u32 hsA[2][4][64][4];   // 8KB dbuf [db][kgl][m][q]
    __shared__ __align__(16) float st[16][260];      // 16.6KB epilogue staging

    int t = threadIdx.x;
    int jt = blockIdx.x, it = blockIdx.y, b = blockIdx.z;
    int i0 = it * 8, j0 = jt * 8;
    int m = t & 63, wv = t >> 6;       // lane == m; wave id wv
    int ii = m >> 3, jj = m & 7;
    int l4 = m >> 4, l16 = m & 15;

    // block-start staging
    #pragma unroll
    for (int q = 0; q < 8; ++q)
        watb_s[t][q] = (q < 6) ? Wat[q * 256 + t] : (q == 6 ? b_alpha[t] : 0.f);
    float relv2[6];
    #pragma unroll
    for (int c = 0; c < 6; ++c)
        relv2[c] = rel[((b * 256 + i0 + ii) * 256 + j0 + jj) * 6 + c];
    float adjv = adj2[(b * 256 + i0 + ii) * 256 + j0 + jj];
    float* ahbase = &ahpart[(((jt * 4 + b) * 32 + it) * 8 + ii) * 256];
    const float* xirow = &xi0[(b * 256 + i0 + ii) * 256];
    const float* xjrow = &xj0b[(b * 256 + j0 + jj) * 256];

    f32x4 acc[4][4];
    #pragma unroll
    for (int a = 0; a < 4; ++a)
        #pragma unroll
        for (int c = 0; c < 4; ++c)
            acc[a][c] = (f32x4){0.f, 0.f, 0.f, 0.f};

    // prologue prefetch: chunk 0's xi/xj slices
    float4 pxi0 = *(const float4*)&xirow[wv * 8];
    float4 pxi1 = *(const float4*)&xirow[wv * 8 + 4];
    float4 pxj0 = *(const float4*)&xjrow[wv * 8];
    float4 pxj1 = *(const float4*)&xjrow[wv * 8 + 4];

    __syncthreads();   // watb_s ready

    for (int c = 0; c < 8; ++c) {
        int db = c & 1;
        int kb = c * 32 + wv * 8;
        float xiarr[8], xjarr[8];
        xiarr[0]=pxi0.x; xiarr[1]=pxi0.y; xiarr[2]=pxi0.z; xiarr[3]=pxi0.w;
        xiarr[4]=pxi1.x; xiarr[5]=pxi1.y; xiarr[6]=pxi1.z; xiarr[7]=pxi1.w;
        xjarr[0]=pxj0.x; xjarr[1]=pxj0.y; xjarr[2]=pxj0.z; xjarr[3]=pxj0.w;
        xjarr[4]=pxj1.x; xjarr[5]=pxj1.y; xjarr[6]=pxj1.z; xjarr[7]=pxj1.w;
        if (c < 7) {   // prefetch next chunk (latency hides under this chunk)
            int kn = kb + 32;
            pxi0 = *(const float4*)&xirow[kn];
            pxi1 = *(const float4*)&xirow[kn + 4];
            pxj0 = *(const float4*)&xjrow[kn];
            pxj1 = *(const float4*)&xjrow[kn + 4];
        }
        float h[8];
        #pragma unroll
        for (int i = 0; i < 8; ++i) {
            int k = kb + i;
            float4 wa = *(const float4*)&watb_s[k][0];   // uniform-address broadcast
            float4 wc = *(const float4*)&watb_s[k][4];
            float a = relv2[0]*wa.x + relv2[1]*wa.y + relv2[2]*wa.z + relv2[3]*wa.w
                    + relv2[4]*wc.x + relv2[5]*wc.y + wc.z;   // wc.z = b_alpha[k]
            h[i] = fmaxf(xiarr[i] + xjarr[i] + a, 0.f);
        }
        // ---- AH0 partial: butterfly over jj, lane jj keeps element jj ----
        {
            float ahv = 0.f;
            #pragma unroll
            for (int i = 0; i < 8; ++i) {
                float v = adjv * h[i];
                v += __shfl_xor(v, 1);
                v += __shfl_xor(v, 2);
                v += __shfl_xor(v, 4);
                ahv = (jj == i) ? v : ahv;
            }
            ahbase[kb + jj] = ahv;
        }
        // ---- bf16 pack (hi only), write to hsA[db] ----
        {
            u32 hi[4];
            #pragma unroll
            for (int p = 0; p < 4; ++p)
                hi[p] = pk2(h[2*p], h[2*p+1]);
            *(uint4*)&hsA[db][wv][m][0] = make_uint4(hi[0], hi[1], hi[2], hi[3]);
        }
        __syncthreads();   // hsA[db] ready — single barrier per chunk (dbuf)

        // ---- fragments + MFMA: A from LDS, B straight from global (L1/L2) ----
        bf16x8 aH[4];
        #pragma unroll
        for (int mt = 0; mt < 4; ++mt)
            aH[mt] = *(const bf16x8*)&hsA[db][l4][mt * 16 + l16][0];
        const u32* wc0 = &wTp[(c * 4 + l4) * 1024];          // hl=0 chunk base
        const u32* wc1 = &wTp[((8 + c) * 4 + l4) * 1024];    // hl=1 chunk base
        #pragma unroll
        for (int ntl = 0; ntl < 4; ++ntl) {
            int n = (wv * 4 + ntl) * 16 + l16;
            bf16x8 bH = *(const bf16x8*)&wc0[n * 4];
            bf16x8 bL = *(const bf16x8*)&wc1[n * 4];
            #pragma unroll
            for (int mt = 0; mt < 4; ++mt) {
                acc[mt][ntl] = __builtin_amdgcn_mfma_f32_16x16x32_bf16(aH[mt], bH, acc[mt][ntl], 0, 0, 0);
                acc[mt][ntl] = __builtin_amdgcn_mfma_f32_16x16x32_bf16(aH[mt], bL, acc[mt][ntl], 0, 0, 0);
            }
        }
        // no trailing barrier: next chunk writes hsA[db^1]
    }

    // ---- epilogue: relu + bf16-pack alpha1 via LDS staging (st disjoint from
    // hsA; per-thread st writes are disjoint; barrier precedes cross-reads) ----
    #pragma unroll
    for (int mt = 0; mt < 4; ++mt) {
        #pragma unroll
        for (int ntl = 0; ntl < 4; ++ntl) {
            int n = (wv * 4 + ntl) * 16 + l16;
            #pragma unroll
            for (int r = 0; r < 4; ++r)
                st[l4 * 4 + r][n] = acc[mt][ntl][r];
        }
        __syncthreads();
        #pragma unroll
        for (int p = 0; p < 2; ++p) {
            int f = p * 256 + t;                     // 0..511
            int row = f >> 5, u8 = f & 31;           // row 0..15, 8 f32 each
            float4 c0 = *(const float4*)&st[row][u8 * 8];
            float4 c1 = *(const float4*)&st[row][u8 * 8 + 4];
            uint4 pk;
            pk.x = pk2(fmaxf(c0.x, 0.f), fmaxf(c0.y, 0.f));
            pk.y = pk2(fmaxf(c0.z, 0.f), fmaxf(c0.w, 0.f));
            pk.z = pk2(fmaxf(c1.x, 0.f), fmaxf(c1.y, 0.f));
            pk.w = pk2(fmaxf(c1.z, 0.f), fmaxf(c1.w, 0.f));
            int mg = mt * 16 + row;                  // pair row 0..63
            int iw = mg >> 3, jw = mg & 7;
            *(uint4*)&alpha1[((b * 256 + i0 + iw) * 256 + j0 + jw) * 128 + u8 * 4] = pk;
        }
        __syncthreads();
    }
}

// ---------------------------------------------------------------------------
// post0: 4 rows per block (weights read once per 4 rows -> 4x less L2 traffic).
// Fuses: reduce_ah -> x1 = relu(AH0 @ w_node0) -> xi1/xj1b projections.
// Per-row FMA order identical to 1-row version (bit-identical results).
// ---------------------------------------------------------------------------
__global__ __launch_bounds__(256) void post0(
    const float* __restrict__ part, const float* __restrict__ w_node0,
    const float* __restrict__ w_vi1, const float* __restrict__ w_vj1,
    const float* __restrict__ bias_h1,
    float* __restrict__ xi1, float* __restrict__ xj1b)
{
    __shared__ __align__(16) float ah_s[4][256];
    __shared__ __align__(16) float x1_s[4][256];
    int bi0 = blockIdx.x * 4;          // 256 blocks; 4 consecutive rows, same b
    int b = bi0 >> 8;
    int t = threadIdx.x;
    #pragma unroll
    for (int r = 0; r < 4; ++r) {
        int i = (bi0 + r) & 255;
        int it = i >> 3, ii = i & 7;
        float s = 0.f;
        #pragma unroll 4
        for (int jt = 0; jt < 32; ++jt)
            s += part[(((jt * 4 + b) * 32 + it) * 8 + ii) * 256 + t];
        ah_s[r][t] = s;
    }
    __syncthreads();
    float a0[4] = {};
    #pragma unroll 8
    for (int k = 0; k < 256; ++k) {
        float w0 = w_node0[k * 256 + t];
        #pragma unroll
        for (int r = 0; r < 4; ++r) a0[r] += ah_s[r][k] * w0;
    }
    #pragma unroll
    for (int r = 0; r < 4; ++r) x1_s[r][t] = fmaxf(a0[r], 0.f);
    __syncthreads();
    float a1[4] = {}, a2[4] = {};
    #pragma unroll 8
    for (int k = 0; k < 256; ++k) {
        float w1 = w_vi1[k * 256 + t];
        float w2 = w_vj1[k * 256 + t];
        #pragma unroll
        for (int r = 0; r < 4; ++r) {
            float xv = x1_s[r][k];
            a1[r] += xv * w1;
            a2[r] += xv * w2;
        }
    }
    #pragma unroll
    for (int r = 0; r < 4; ++r) {
        int i = (bi0 + r) & 255;
        xi1[(bi0 + r) * 256 + t] = a1[r];
        xj1b[(bi0 + r) * 256 + t] = a2[r] + bias_h1[i * 256 + t];
    }
}

// ---------------------------------------------------------------------------
// pass2x: 2 rows per block (xj1b + w_node1 read once for both rows).
// Stream bf16 alpha1, accumulate AH1, fused final x2 = relu(AH1 @ w_node1).
// ---------------------------------------------------------------------------
__global__ __launch_bounds__(256) void pass2x(
    const u32* __restrict__ alpha1, const float* __restrict__ xi1,
    const float* __restrict__ xj1b, const float* __restrict__ adj2,
    const float* __restrict__ w_node1, float* __restrict__ x2)
{
    __shared__ __align__(16) float partial[4][2][256];
    __shared__ __align__(16) float ah1_s[2][256];
    int bi0 = blockIdx.x * 2;          // 512 blocks; rows bi0, bi0+1 (same b)
    int b = bi0 >> 8;
    int t = threadIdx.x;
    int wv = t >> 6, lane = t & 63;
    int k4 = lane * 4;
    float4 xiA = *(const float4*)&xi1[bi0 * 256 + k4];
    float4 xiB = *(const float4*)&xi1[(bi0 + 1) * 256 + k4];
    float4 accA = {0.f, 0.f, 0.f, 0.f};
    float4 accB = {0.f, 0.f, 0.f, 0.f};
    size_t baseA = (size_t)bi0 * 32768;   // u32 units: 256*128
    size_t baseB = baseA + 32768;
    const float* a2A = &adj2[bi0 * 256];
    const float* a2B = a2A + 256;
    for (int j = wv; j < 256; j += 4) {
        float4 xj = *(const float4*)&xj1b[(b * 256 + j) * 256 + k4];
        float aA = a2A[j], aB = a2B[j];
        uint2 qA = *(const uint2*)&alpha1[baseA + j * 128 + (k4 >> 1)];
        uint2 qB = *(const uint2*)&alpha1[baseB + j * 128 + (k4 >> 1)];
        float4 alA, alB;
        alA.x = bf2f(qA.x & 0xFFFFu); alA.y = bf2f(qA.x >> 16);
        alA.z = bf2f(qA.y & 0xFFFFu); alA.w = bf2f(qA.y >> 16);
        alB.x = bf2f(qB.x & 0xFFFFu); alB.y = bf2f(qB.x >> 16);
        alB.z = bf2f(qB.y & 0xFFFFu); alB.w = bf2f(qB.y >> 16);
        accA.x += aA * fmaxf(xiA.x + xj.x + alA.x, 0.f);
        accA.y += aA * fmaxf(xiA.y + xj.y + alA.y, 0.f);
        accA.z += aA * fmaxf(xiA.z + xj.z + alA.z, 0.f);
        accA.w += aA * fmaxf(xiA.w + xj.w + alA.w, 0.f);
        accB.x += aB * fmaxf(xiB.x + xj.x + alB.x, 0.f);
        accB.y += aB * fmaxf(xiB.y + xj.y + alB.y, 0.f);
        accB.z += aB * fmaxf(xiB.z + xj.z + alB.z, 0.f);
        accB.w += aB * fmaxf(xiB.w + xj.w + alB.w, 0.f);
    }
    *(float4*)&partial[wv][0][k4] = accA;
    *(float4*)&partial[wv][1][k4] = accB;
    __syncthreads();
    ah1_s[0][t] = partial[0][0][t] + partial[1][0][t] + partial[2][0][t] + partial[3][0][t];
    ah1_s[1][t] = partial[0][1][t] + partial[1][1][t] + partial[2][1][t] + partial[3][1][t];
    __syncthreads();
    float o0 = 0.f, o1 = 0.f;
    #pragma unroll 8
    for (int k = 0; k < 256; ++k) {
        float w = w_node1[k * 256 + t];
        o0 += ah1_s[0][k] * w;
        o1 += ah1_s[1][k] * w;
    }
    x2[bi0 * 256 + t] = fmaxf(o0, 0.f);
    x2[(bi0 + 1) * 256 + t] = fmaxf(o1, 0.f);
}

// ---------------------------------------------------------------------------
// Tier C fallback kernels (tiny-ws path)
// ---------------------------------------------------------------------------
__global__ __launch_bounds__(256) void pass1C(
    const float* __restrict__ rel, const float* __restrict__ Wat,
    const float* __restrict__ b_alpha, const float* __restrict__ xi0,
    const float* __restrict__ xj0b, const float* __restrict__ adj2,
    float* __restrict__ AH0)
{
    __shared__ float xj_s[16][257];
    __shared__ float rel_s[16 * 48];
    __shared__ float adj_sC[128];
    int t = threadIdx.x;
    int it = blockIdx.x, b = blockIdx.y;
    int i0 = it * 8;
    float xiv[8], watv[6];
    #pragma unroll
    for (int ii = 0; ii < 8; ++ii) xiv[ii] = xi0[(b * 256 + i0 + ii) * 256 + t];
    #pragma unroll
    for (int c = 0; c < 6; ++c) watv[c] = Wat[c * 256 + t];
    float bav = b_alpha[t];
    float ah[8] = {};
    for (int jc = 0; jc < 256; jc += 16) {
        __syncthreads();
        #pragma unroll
        for (int q = 0; q < 16; ++q) xj_s[q][t] = xj0b[(b * 256 + jc + q) * 256 + t];
        for (int e = t; e < 768; e += 256) {
            int jjp = e / 48, r = e % 48;
            rel_s[e] = rel[((b * 256 + i0 + r / 6) * 256 + jc + jjp) * 6 + (r % 6)];
        }
        if (t < 128) adj_sC[t] = adj2[(b * 256 + i0 + (t & 7)) * 256 + jc + (t >> 3)];
        __syncthreads();
        for (int jjp = 0; jjp < 16; ++jjp) {
            float xjv = xj_s[jjp][t];
            #pragma unroll
            for (int ii = 0; ii < 8; ++ii) {
                float a = bav;
                #pragma unroll
                for (int c = 0; c < 6; ++c) a += rel_s[jjp * 48 + ii * 6 + c] * watv[c];
                float h = fmaxf(xiv[ii] + xjv + a, 0.f);
                ah[ii] += adj_sC[jjp * 8 + ii] * h;
            }
        }
    }
    #pragma unroll
    for (int ii = 0; ii < 8; ++ii)
        AH0[(b * 256 + i0 + ii) * 256 + t] = ah[ii];
}

__global__ __launch_bounds__(256) void pass2C(
    const float* __restrict__ rel, const float* __restrict__ Wat,
    const float* __restrict__ b_alpha, const float* __restrict__ xi0,
    const float* __restrict__ xj0b, const float* __restrict__ w_alpha0,
    const float* __restrict__ xi1, const float* __restrict__ xj1b,
    const float* __restrict__ adj2, float* __restrict__ AH1)
{
    __shared__ float xi_s[8][257];
    __shared__ float xj_s[8][257];
    __shared__ float xj1_s[8][257];
    __shared__ __align__(16) float wat_s[6][256];
    __shared__ __align__(16) float ba_s[256];
    __shared__ __align__(16) float rel_s[6][64];
    __shared__ __align__(16) float adj_s[64];
    __shared__ __align__(16) float hs[16][64];
    __shared__ __align__(16) float ws_s[16][256];

    int t = threadIdx.x;
    int it = blockIdx.x, b = blockIdx.y;
    int i0 = it * 8;
    int rg = t >> 5, cg = t & 31;
    int lane = t & 63, wv = t >> 6;
    int ii_l = lane >> 3, jj_l = lane & 7;

    #pragma unroll
    for (int q = 0; q < 8; ++q) xi_s[q][t] = xi0[(b * 256 + i0 + q) * 256 + t];
    #pragma unroll
    for (int q = 0; q < 6; ++q) wat_s[q][t] = Wat[q * 256 + t];
    ba_s[t] = b_alpha[t];
    float xi1v[8];
    #pragma unroll
    for (int y = 0; y < 8; ++y) xi1v[y] = xi1[(b * 256 + i0 + rg) * 256 + cg * 8 + y];
    float ah1[8] = {};

    for (int jt = 0; jt < 32; ++jt) {
        int j0 = jt * 8;
        __syncthreads();
        #pragma unroll
        for (int q = 0; q < 8; ++q) {
            xj_s[q][t]  = xj0b[(b * 256 + j0 + q) * 256 + t];
            xj1_s[q][t] = xj1b[(b * 256 + j0 + q) * 256 + t];
        }
        for (int e = t; e < 384; e += 256) {
            int ii = e / 48, rem = e % 48;
            int jjp = rem / 6, c = rem % 6;
            rel_s[c][ii * 8 + jjp] = rel[((b * 256 + i0 + ii) * 256 + j0 + jjp) * 6 + c];
        }
        if (t < 64) adj_s[t] = adj2[(b * 256 + i0 + (t >> 3)) * 256 + j0 + (t & 7)];

        float acc[8][8] = {};
        for (int c = 0; c < 16; ++c) {
            __syncthreads();
            #pragma unroll
            for (int p = 0; p < 4; ++p) {
                int klocal = wv + p * 4;
                int kg = c * 16 + klocal;
                float a = ba_s[kg];
                #pragma unroll
                for (int cc = 0; cc < 6; ++cc) a += rel_s[cc][lane] * wat_s[cc][kg];
                float h = xi_s[ii_l][kg] + xj_s[jj_l][kg] + a;
                hs[klocal][lane] = fmaxf(h, 0.f);
            }
            #pragma unroll
            for (int q = 0; q < 4; ++q) {
                int f = q * 256 + t;
                int row = f >> 6, col4 = f & 63;
                *(float4*)&ws_s[row][col4 * 4] =
                    *(const float4*)&w_alpha0[(c * 16 + row) * 256 + col4 * 4];
            }
            __syncthreads();
            #pragma unroll
            for (int kk = 0; kk < 16; ++kk) {
                float4 a0 = *(const float4*)&hs[kk][rg * 8];
                float4 a1 = *(const float4*)&hs[kk][rg * 8 + 4];
                float4 b0 = *(const float4*)&ws_s[kk][cg * 8];
                float4 b1 = *(const float4*)&ws_s[kk][cg * 8 + 4];
                float av[8] = {a0.x, a0.y, a0.z, a0.w, a1.x, a1.y, a1.z, a1.w};
                float bv[8] = {b0.x, b0.y, b0.z, b0.w, b1.x, b1.y, b1.z, b1.w};
                #pragma unroll
                for (int x = 0; x < 8; ++x)
                    #pragma unroll
                    for (int y = 0; y < 8; ++y)
                        acc[x][y] += av[x] * bv[y];
            }
        }
        #pragma unroll
        for (int x = 0; x < 8; ++x) {
            float a2 = adj_s[rg * 8 + x];
            #pragma unroll
            for (int y = 0; y < 8; ++y) {
                float al = fmaxf(acc[x][y], 0.f);
                float h1 = fmaxf(xi1v[y] + xj1_s[x][cg * 8 + y] + al, 0.f);
                ah1[y] += a2 * h1;
            }
        }
    }
    #pragma unroll
    for (int y = 0; y < 8; ++y)
        AH1[(b * 256 + i0 + rg) * 256 + cg * 8 + y] = ah1[y];
}

// ---------------------------------------------------------------------------
extern "C" void kernel_launch(void* const* d_in, const int* in_sizes, int n_in,
                              void* d_out, int out_size, void* d_ws, size_t ws_size,
                              hipStream_t stream)
{
    const float* x        = (const float*)d_in[0];
    const float* rel      = (const float*)d_in[1];
    const float* adj      = (const float*)d_in[2];
    const int*   box_num  = (const int*)d_in[3];
    const float* Wat      = (const float*)d_in[4];
    const float* b_alpha  = (const float*)d_in[5];
    const float* W_proj   = (const float*)d_in[6];
    const float* b_proj   = (const float*)d_in[7];
    const float* learn_w  = (const float*)d_in[8];
    const float* w_alpha0 = (const float*)d_in[9];
    const float* w_vi0    = (const float*)d_in[10];
    const float* w_vj0    = (const float*)d_in[11];
    const float* bias_h0  = (const float*)d_in[12];
    const float* w_node0  = (const float*)d_in[13];
    // d_in[14] = l1_w_alpha (unused: layer-1 new_alpha is discarded)
    const float* w_vi1    = (const float*)d_in[15];
    const float* w_vj1    = (const float*)d_in[16];
    const float* bias_h1  = (const float*)d_in[17];
    const float* w_node1  = (const float*)d_in[18];

    // ---- workspace layout ----
    float* sm    = (float*)d_ws;
    float* adj2  = sm;                 // 262,144
    float* xhat  = adj2  + 262144;     // 131,072
    float* xi0   = xhat  + 131072;     // 262,144
    float* xj0b  = xi0   + 262144;     // 262,144
    float* AH0   = xj0b  + 262144;     // 262,144 (fallback AH0; mfma path uses as xhatT)
    float* x1    = AH0   + 262144;     // 262,144 (fallback path only)
    float* xi1   = x1    + 262144;     // 262,144
    float* xj1b  = xi1   + 262144;     // 262,144
    float* AH1   = xj1b  + 262144;     // 262,144 (fallback path only)
    float* rowP1 = AH1   + 262144;     //   1,024
    float* rowP2 = rowP1 + 1024;       //   1,024
    float* xhatT = AH0;                // alias: consumed before pass1C writes AH0
    const size_t SMALLS_F = 2230272;   // floats
    const size_t WTP_F    = 65536;     // 256 KB packed hi/lo W
    const size_t PART_F   = 8388608;
    u32*   wTp    = (u32*)(sm + SMALLS_F);
    float* part   = sm + SMALLS_F + WTP_F;
    u32*   alpha1 = (u32*)(sm + SMALLS_F + WTP_F + PART_F);   // bf16-packed, 128 MiB

    const size_t needM = (SMALLS_F + WTP_F + PART_F) * 4ULL + 134217728ULL;  // ~169 MB
    int use_mfma = (ws_size >= needM);

    float* out_x2   = (float*)d_out;
    float* out_soft = out_x2 + 262144;
    float* out_gl   = out_soft + 262144;

    // W prep (independent of everything else) first
    if (use_mfma) wprep<<<32, 256, 0, stream>>>(w_alpha0, wTp);

    // Phase A projections, fused: xhat (+xhatT) + xi0 + xj0b
    {
        GJob ja{x, W_proj, b_proj, nullptr, xhat, xhatT, 256, 128, 0};
        GJob jb{x, w_vi0,  nullptr, nullptr, xi0,  nullptr, 256, 256, 0};
        GJob jc{x, w_vj0,  nullptr, bias_h0, xj0b, nullptr, 256, 256, 0};
        gemm64_multi<<<dim3(16, 4, 3), 256, 0, stream>>>(ja, jb, jc);
    }
    soft_adj_kernel<<<1024, 256, 0, stream>>>(xhat, xhatT, adj, box_num, learn_w, out_soft, adj2, rowP1, rowP2);
    gl_loss_kernel<<<4, 256, 0, stream>>>(rowP1, rowP2, box_num, out_gl);

    if (use_mfma) {
        // Layer 0 heavy pass -> alpha1 (bf16) + AH0 partials
        pass1M<<<dim3(32, 32, 4), 256, 0, stream>>>(rel, Wat, b_alpha, xi0, xj0b, adj2, wTp, alpha1, part);
        // Fused: reduce AH0 -> x1 -> xi1/xj1b (4 rows/block)
        post0<<<256, 256, 0, stream>>>(part, w_node0, w_vi1, w_vj1, bias_h1, xi1, xj1b);
        // Layer 1 + fused final node update -> x2 (2 rows/block)
        pass2x<<<512, 256, 0, stream>>>(alpha1, xi1, xj1b, adj2, w_node1, out_x2);
    } else {
        pass1C<<<dim3(32, 4), 256, 0, stream>>>(rel, Wat, b_alpha, xi0, xj0b, adj2, AH0);
        gemm64<<<dim3(16, 4), 256, 0, stream>>>(AH0, w_node0, nullptr, nullptr, x1, 1024, 256, 256, 1);
        {
            GJob j1a{x1, w_vi1, nullptr, nullptr, xi1,  nullptr, 256, 256, 0};
            GJob j1b{x1, w_vj1, nullptr, bias_h1, xj1b, nullptr, 256, 256, 0};
            gemm64_multi<<<dim3(16, 4, 2), 256, 0, stream>>>(j1a, j1b, j1b);
        }
        pass2C<<<dim3(32, 4), 256, 0, stream>>>(rel, Wat, b_alpha, xi0, xj0b, w_alpha0, xi1, xj1b, adj2, AH1);
        gemm64<<<dim3(16, 4), 256, 0, stream>>>(AH1, w_node1, nullptr, nullptr, out_x2, 1024, 256, 256, 1);
    }
}